// Round 2
// baseline (599.519 us; speedup 1.0000x reference)
//
#include <hip/hip_runtime.h>
#include <stdint.h>

#define BB 32
#define CC 512
#define HW 4096     // 64*64
#define HID 32      // C / 16
#define CB 8        // batches per chunk (67 MB of x -> fits L3 with room to spare)
#define NCHUNK (BB / CB)              // 4
#define PLANES_PER_CHUNK (CB * CC)    // 4096

typedef float f4 __attribute__((ext_vector_type(4)));

// ---------------------------------------------------------------------------
// Kernel 1: global average pool over H*W per plane, for one chunk of batches.
// One block per plane; 256 threads; 4 x float4 loads per thread (16 KiB/plane).
// Reads allocate the chunk's x into L3 for the scale pass to hit.
// ---------------------------------------------------------------------------
__global__ __launch_bounds__(256) void se_pool(const float* __restrict__ x,
                                               float* __restrict__ v,
                                               int plane0) {
    const int plane = plane0 + blockIdx.x;
    const f4* __restrict__ p4 = (const f4*)(x + (size_t)plane * HW);
    const int t = threadIdx.x;

    float s = 0.f;
#pragma unroll
    for (int it = 0; it < 4; ++it) {
        f4 d = p4[it * 256 + t];
        s += d.x + d.y + d.z + d.w;
    }
    // wave-64 shuffle reduction
#pragma unroll
    for (int off = 32; off > 0; off >>= 1) s += __shfl_down(s, off, 64);

    __shared__ float ws[4];
    const int lane = t & 63, wid = t >> 6;
    if (lane == 0) ws[wid] = s;
    __syncthreads();
    if (t == 0) {
        float tot = ws[0] + ws[1] + ws[2] + ws[3];
        v[plane] = tot * (1.0f / (float)HW);
    }
}

// ---------------------------------------------------------------------------
// Kernel 2: tiny MLP gate for one chunk (CB batches).
// h = relu(v @ w1^T) [CB x HID]; g = sigmoid(h @ w2^T) [CB x CC].
// Single block, 1024 threads; 256 dots x 4 threads each, float4-vectorized.
// ---------------------------------------------------------------------------
__global__ __launch_bounds__(1024) void se_mlp(const float* __restrict__ v,
                                               const float* __restrict__ w1,
                                               const float* __restrict__ w2,
                                               float* __restrict__ g,
                                               int b0) {
    __shared__ float vs[CB * CC];    // 16 KiB
    __shared__ float h[CB * HID];    // 1 KiB
    const int t = threadIdx.x;

    for (int i = t; i < CB * CC; i += 1024) vs[i] = v[b0 * CC + i];
    __syncthreads();

    // h: CB*HID = 256 dot products of length CC, 4 threads per dot.
    {
        const int dot = t >> 2, sub = t & 3;        // dot in [0,256)
        const int b = dot >> 5, j = dot & (HID - 1);
        const f4* __restrict__ wr = (const f4*)(w1 + j * CC) + sub * 32;
        const f4* __restrict__ vr = (const f4*)(vs + b * CC) + sub * 32;
        float s = 0.f;
#pragma unroll
        for (int i = 0; i < 32; ++i) {
            f4 a = vr[i], w = wr[i];
            s += a.x * w.x + a.y * w.y + a.z * w.z + a.w * w.w;
        }
        s += __shfl_xor(s, 1, 64);
        s += __shfl_xor(s, 2, 64);
        if (sub == 0) h[dot] = s > 0.f ? s : 0.f;
    }
    __syncthreads();

    // g: CB*CC = 4096 gates, 4 per thread, float4 over HID.
    for (int e = t; e < CB * CC; e += 1024) {
        const int b = e >> 9, c = e & (CC - 1);
        const f4* __restrict__ wr = (const f4*)(w2 + c * HID);
        const f4* __restrict__ hr = (const f4*)(h + b * HID);
        float s = 0.f;
#pragma unroll
        for (int q = 0; q < HID / 4; ++q) {
            f4 a = hr[q], w = wr[q];
            s += a.x * w.x + a.y * w.y + a.z * w.z + a.w * w.w;
        }
        g[b0 * CC + e] = 1.0f / (1.0f + __expf(-s));
    }
}

// ---------------------------------------------------------------------------
// Kernel 3: out = x * g[plane] for one chunk. Reverse plane order within the
// chunk (most-recently-cached first); nontemporal stores keep the out stream
// from evicting the chunk's x from L3.
// ---------------------------------------------------------------------------
__global__ __launch_bounds__(256) void se_scale(const float* __restrict__ x,
                                                const float* __restrict__ g,
                                                float* __restrict__ out,
                                                int plane0) {
    const int plane = plane0 + (PLANES_PER_CHUNK - 1 - (int)blockIdx.x);
    const float gate = g[plane];
    const f4* __restrict__ xp = (const f4*)(x + (size_t)plane * HW);
    f4* __restrict__ op = (f4*)(out + (size_t)plane * HW);
    const int t = threadIdx.x;

#pragma unroll
    for (int it = 0; it < 4; ++it) {
        f4 d = xp[it * 256 + t];
        d.x *= gate; d.y *= gate; d.z *= gate; d.w *= gate;
        __builtin_nontemporal_store(d, &op[it * 256 + t]);
    }
}

extern "C" void kernel_launch(void* const* d_in, const int* in_sizes, int n_in,
                              void* d_out, int out_size, void* d_ws, size_t ws_size,
                              hipStream_t stream) {
    const float* x  = (const float*)d_in[0];  // [B][C][H][W] fp32
    const float* w1 = (const float*)d_in[1];  // [HID][C] fp32
    const float* w2 = (const float*)d_in[2];  // [C][HID] fp32
    float* out = (float*)d_out;               // [B][C][H][W] fp32

    float* v = (float*)d_ws;          // B*C fp32  (64 KiB)
    float* g = v + BB * CC;           // B*C fp32  (64 KiB)

    for (int k = 0; k < NCHUNK; ++k) {
        const int b0 = k * CB;
        const int plane0 = b0 * CC;
        se_pool <<<PLANES_PER_CHUNK, 256, 0, stream>>>(x, v, plane0);
        se_mlp  <<<1, 1024, 0, stream>>>(v, w1, w2, g, b0);
        se_scale<<<PLANES_PER_CHUNK, 256, 0, stream>>>(x, g, out, plane0);
    }
}